// Round 1
// baseline (407.029 us; speedup 1.0000x reference)
//
#include <hip/hip_runtime.h>

#define NN 50000
#define NE 800000
#define DD 64
#define NEG 0.2f

__device__ __forceinline__ unsigned fkey(float f) {
    unsigned b = __float_as_uint(f);
    return (b & 0x80000000u) ? ~b : (b | 0x80000000u);
}
__device__ __forceinline__ float fdec(unsigned k) {
    unsigned b = (k & 0x80000000u) ? (k ^ 0x80000000u) : ~k;
    return __uint_as_float(b);
}

// 1. init: zero h_agg (in d_out) and denom, set maxkey = encode(-inf)
__global__ __launch_bounds__(256) void k_init(float* hagg, float* denom, unsigned* maxkey) {
    int i = blockIdx.x * 256 + threadIdx.x;     // grid covers NN*DD
    hagg[i] = 0.f;
    if (i < NN) { denom[i] = 0.f; maxkey[i] = 0x007FFFFFu; }  // ~bits(-inf)
}

// 2. h = feat @ W^T   (W is [out,in]; h[n,o] = sum_i feat[n,i]*W[o,i])
__global__ __launch_bounds__(256) void k_gemm(const float* __restrict__ feat,
                                              const float* __restrict__ W,
                                              float* __restrict__ h) {
    __shared__ float sWt[64][65];   // sWt[i][o] = W[o][i], padded vs bank conflicts
    __shared__ float sF[4][64];
    const int tx = threadIdx.x, ty = threadIdx.y;
    const int t = ty * 64 + tx;
    for (int k = t; k < 4096; k += 256) {
        int o = k >> 6, i = k & 63;
        sWt[i][o] = W[k];
    }
    const int n = blockIdx.x * 4 + ty;          // NN % 4 == 0
    sF[ty][tx] = feat[n * 64 + tx];
    __syncthreads();
    float acc = 0.f;
#pragma unroll
    for (int i = 0; i < 64; ++i) acc = fmaf(sF[ty][i], sWt[i][tx], acc);
    h[n * 64 + tx] = acc;
}

// 3. scatter-sum: h_agg[dst] += h[src], one wave (64 lanes) per edge
__global__ __launch_bounds__(256) void k_scatter(const float* __restrict__ h,
                                                 const int* __restrict__ src,
                                                 const int* __restrict__ dst,
                                                 float* __restrict__ hagg) {
    const int e = blockIdx.x * 4 + threadIdx.y;  // NE % 4 == 0
    const int s = src[e], d = dst[e];
    atomicAdd(&hagg[d * 64 + threadIdx.x], h[s * 64 + threadIdx.x]);
}

// 4. t = tanh(h_agg)
__global__ __launch_bounds__(256) void k_tanh(const float* __restrict__ hagg,
                                              float* __restrict__ t) {
    int i = blockIdx.x * 256 + threadIdx.x;     // grid covers NN*DD
    t[i] = tanhf(hagg[i]);
}

// 5. e = leakyrelu(dot(h_agg[src], t[dst])), atomicMax per dst
__global__ __launch_bounds__(256) void k_edgedot(const float* __restrict__ hagg,
                                                 const float* __restrict__ tn,
                                                 const int* __restrict__ src,
                                                 const int* __restrict__ dst,
                                                 float* __restrict__ ebuf,
                                                 unsigned* __restrict__ maxkey) {
    const int e = blockIdx.x * 4 + threadIdx.y;
    const int s = src[e], d = dst[e];
    float v = hagg[s * 64 + threadIdx.x] * tn[d * 64 + threadIdx.x];
#pragma unroll
    for (int off = 32; off; off >>= 1) v += __shfl_xor(v, off, 64);
    if (threadIdx.x == 0) {
        float ev = v >= 0.f ? v : NEG * v;
        ebuf[e] = ev;
        atomicMax(&maxkey[d], fkey(ev));
    }
}

// 6. x = exp(e - max[dst]); denom[dst] += x
__global__ __launch_bounds__(256) void k_exp(const int* __restrict__ dst,
                                             const unsigned* __restrict__ maxkey,
                                             float* __restrict__ ebuf,
                                             float* __restrict__ denom) {
    int i = blockIdx.x * 256 + threadIdx.x;     // NE % 256 == 0
    int d = dst[i];
    float x = expf(ebuf[i] - fdec(maxkey[d]));
    ebuf[i] = x;
    atomicAdd(&denom[d], x);
}

// 7. e_soft = x / denom[dst]
__global__ __launch_bounds__(256) void k_div(const int* __restrict__ dst,
                                             const float* __restrict__ ebuf,
                                             const float* __restrict__ denom,
                                             float* __restrict__ out_e) {
    int i = blockIdx.x * 256 + threadIdx.x;
    out_e[i] = ebuf[i] / denom[dst[i]];
}

extern "C" void kernel_launch(void* const* d_in, const int* in_sizes, int n_in,
                              void* d_out, int out_size, void* d_ws, size_t ws_size,
                              hipStream_t stream) {
    const float* feat = (const float*)d_in[0];
    const float* W    = (const float*)d_in[1];
    const int*   src  = (const int*)d_in[2];
    const int*   dst  = (const int*)d_in[3];

    float* out    = (float*)d_out;
    float* hagg   = out;               // NN*DD
    float* e_soft = out + NN * DD;     // NE

    float*    h      = (float*)d_ws;            // NN*DD
    float*    t      = h + NN * DD;             // NN*DD
    float*    ebuf   = t + NN * DD;             // NE
    float*    denom  = ebuf + NE;               // NN
    unsigned* maxkey = (unsigned*)(denom + NN); // NN

    dim3 b64x4(64, 4);
    k_init   <<<NN * DD / 256, 256, 0, stream>>>(hagg, denom, maxkey);
    k_gemm   <<<NN / 4, b64x4, 0, stream>>>(feat, W, h);
    k_scatter<<<NE / 4, b64x4, 0, stream>>>(h, src, dst, hagg);
    k_tanh   <<<NN * DD / 256, 256, 0, stream>>>(hagg, t);
    k_edgedot<<<NE / 4, b64x4, 0, stream>>>(hagg, t, src, dst, ebuf, maxkey);
    k_exp    <<<NE / 256, 256, 0, stream>>>(dst, maxkey, ebuf, denom);
    k_div    <<<NE / 256, 256, 0, stream>>>(dst, ebuf, denom, e_soft);
}

// Round 2
// 306.699 us; speedup vs baseline: 1.3271x; 1.3271x over previous
//
#include <hip/hip_runtime.h>

#define NN 50000
#define NE 800000
#define DD 64
#define NEG 0.2f

// 1. init per-call scratch state
__global__ __launch_bounds__(256) void k_init(int* count, int* cursor) {
    int i = blockIdx.x * 256 + threadIdx.x;
    if (i < NN) { count[i] = 0; cursor[i] = 0; }
}

// 2. h = feat @ W^T   (W is [out,in]; h[n,o] = sum_i feat[n,i]*W[o,i])
__global__ __launch_bounds__(256) void k_gemm(const float* __restrict__ feat,
                                              const float* __restrict__ W,
                                              float* __restrict__ h) {
    __shared__ float sWt[64][65];   // sWt[i][o] = W[o][i]
    __shared__ float sF[4][64];
    const int tx = threadIdx.x, ty = threadIdx.y;
    const int t = ty * 64 + tx;
    for (int k = t; k < 4096; k += 256) {
        int o = k >> 6, i = k & 63;
        sWt[i][o] = W[k];
    }
    const int n = blockIdx.x * 4 + ty;          // NN % 4 == 0
    sF[ty][tx] = feat[n * 64 + tx];
    __syncthreads();
    float acc = 0.f;
#pragma unroll
    for (int i = 0; i < 64; ++i) acc = fmaf(sF[ty][i], sWt[i][tx], acc);
    h[n * 64 + tx] = acc;
}

// 3. degree histogram
__global__ __launch_bounds__(256) void k_count(const int* __restrict__ dst,
                                               int* __restrict__ count) {
    int e = blockIdx.x * 256 + threadIdx.x;     // NE % 256 == 0
    atomicAdd(&count[dst[e]], 1);
}

// 4. exclusive prefix scan of count -> rowptr (one kernel; each block
//    recomputes its global prefix by summing preceding counts: 196 blocks,
//    <5M int reads total, L2-resident)
__global__ __launch_bounds__(256) void k_scan(const int* __restrict__ count,
                                              int* __restrict__ rowptr) {
    __shared__ int sdata[256];
    const int tid = threadIdx.x, b = blockIdx.x;
    int pre = 0;
    for (int i = tid; i < b * 256; i += 256) pre += count[i];
    sdata[tid] = pre;
    __syncthreads();
    for (int off = 128; off; off >>= 1) {
        if (tid < off) sdata[tid] += sdata[tid + off];
        __syncthreads();
    }
    const int P = sdata[0];
    __syncthreads();
    const int idx = b * 256 + tid;
    const int c = (idx < NN) ? count[idx] : 0;
    sdata[tid] = c;
    __syncthreads();
    for (int off = 1; off < 256; off <<= 1) {
        int v = (tid >= off) ? sdata[tid - off] : 0;
        __syncthreads();
        sdata[tid] += v;
        __syncthreads();
    }
    if (idx < NN) rowptr[idx] = P + sdata[tid] - c;   // exclusive
}

// 5. fill CSR slots
__global__ __launch_bounds__(256) void k_fill(const int* __restrict__ src,
                                              const int* __restrict__ dst,
                                              const int* __restrict__ rowptr,
                                              int* __restrict__ cursor,
                                              int* __restrict__ esrc,
                                              int* __restrict__ eidx) {
    int e = blockIdx.x * 256 + threadIdx.x;
    int d = dst[e];
    int p = rowptr[d] + atomicAdd(&cursor[d], 1);
    esrc[p] = src[e];
    eidx[p] = e;
}

// 6. gather aggregation: one wave per dst node, no atomics
__global__ __launch_bounds__(256) void k_agg(const float* __restrict__ h,
                                             const int* __restrict__ rowptr,
                                             const int* __restrict__ count,
                                             const int* __restrict__ esrc,
                                             float* __restrict__ hagg) {
    const int d = blockIdx.x * 4 + threadIdx.y;
    if (d >= NN) return;
    const int lane = threadIdx.x;
    const int start = rowptr[d], len = count[d];
    float acc = 0.f;
    for (int base = 0; base < len; base += 64) {
        const int nb = min(64, len - base);
        int sid = (lane < nb) ? esrc[start + base + lane] : 0;
        for (int j = 0; j < nb; ++j) {
            int s = __shfl(sid, j, 64);
            acc += h[s * 64 + lane];
        }
    }
    hagg[d * 64 + lane] = acc;
}

// 7. fused edge-dot + leaky-relu + edge-softmax: one wave per dst, no atomics
__global__ __launch_bounds__(256) void k_soft(const float* __restrict__ hagg,
                                              const int* __restrict__ rowptr,
                                              const int* __restrict__ count,
                                              const int* __restrict__ esrc,
                                              const int* __restrict__ eidx,
                                              float* __restrict__ ebuf,
                                              float* __restrict__ out_e) {
    const int d = blockIdx.x * 4 + threadIdx.y;
    if (d >= NN) return;
    const int lane = threadIdx.x;
    const int start = rowptr[d], len = count[d];
    if (len == 0) return;
    const float td = tanhf(hagg[d * 64 + lane]);   // once per dst, in-register
    float m = -3.4e38f;
    for (int base = 0; base < len; base += 64) {
        const int nb = min(64, len - base);
        int sid = (lane < nb) ? esrc[start + base + lane] : 0;
        float myev = 0.f;
        for (int j = 0; j < nb; ++j) {
            int s = __shfl(sid, j, 64);
            float v = hagg[s * 64 + lane] * td;
#pragma unroll
            for (int off = 32; off; off >>= 1) v += __shfl_xor(v, off, 64);
            float ev = v >= 0.f ? v : NEG * v;     // uniform across lanes
            m = fmaxf(m, ev);
            if (lane == j) myev = ev;
        }
        if (lane < nb) ebuf[start + base + lane] = myev;
    }
    float ssum = 0.f;
    for (int base = 0; base < len; base += 64) {
        const int nb = min(64, len - base);
        float x = (lane < nb) ? expf(ebuf[start + base + lane] - m) : 0.f;
#pragma unroll
        for (int off = 32; off; off >>= 1) x += __shfl_xor(x, off, 64);
        ssum += x;
    }
    const float inv = 1.f / ssum;
    for (int base = 0; base < len; base += 64) {
        const int nb = min(64, len - base);
        if (lane < nb)
            out_e[eidx[start + base + lane]] =
                expf(ebuf[start + base + lane] - m) * inv;
    }
}

extern "C" void kernel_launch(void* const* d_in, const int* in_sizes, int n_in,
                              void* d_out, int out_size, void* d_ws, size_t ws_size,
                              hipStream_t stream) {
    const float* feat = (const float*)d_in[0];
    const float* W    = (const float*)d_in[1];
    const int*   src  = (const int*)d_in[2];
    const int*   dst  = (const int*)d_in[3];

    float* out    = (float*)d_out;
    float* hagg   = out;               // NN*DD
    float* e_soft = out + NN * DD;     // NE

    float* h    = (float*)d_ws;              // NN*DD f32
    float* ebuf = h + NN * DD;               // NE f32
    int*   count  = (int*)(ebuf + NE);       // NN
    int*   cursor = count + NN;              // NN
    int*   rowptr = cursor + NN;             // NN
    int*   esrc   = rowptr + NN;             // NE
    int*   eidx   = esrc + NE;               // NE

    dim3 b64x4(64, 4);
    k_init <<<(NN + 255) / 256, 256, 0, stream>>>(count, cursor);
    k_gemm <<<NN / 4, b64x4, 0, stream>>>(feat, W, h);
    k_count<<<NE / 256, 256, 0, stream>>>(dst, count);
    k_scan <<<(NN + 255) / 256, 256, 0, stream>>>(count, rowptr);
    k_fill <<<NE / 256, 256, 0, stream>>>(src, dst, rowptr, cursor, esrc, eidx);
    k_agg  <<<(NN + 3) / 4, b64x4, 0, stream>>>(h, rowptr, count, esrc, hagg);
    k_soft <<<(NN + 3) / 4, b64x4, 0, stream>>>(hagg, rowptr, count, esrc, eidx,
                                                ebuf, e_soft);
}

// Round 3
// 287.409 us; speedup vs baseline: 1.4162x; 1.0671x over previous
//
#include <hip/hip_runtime.h>

#define NN 50000
#define NE 800000
#define DD 64
#define NEG 0.2f

__device__ __forceinline__ unsigned fkey(float f) {
    unsigned b = __float_as_uint(f);
    return (b & 0x80000000u) ? ~b : (b | 0x80000000u);
}
__device__ __forceinline__ float fdec(unsigned k) {
    unsigned b = (k & 0x80000000u) ? (k ^ 0x80000000u) : ~k;
    return __uint_as_float(b);
}

// 1. init per-call scratch state
__global__ __launch_bounds__(256) void k_init(int* count, int* cursor,
                                              unsigned* maxkey, float* denom) {
    int i = blockIdx.x * 256 + threadIdx.x;
    if (i < NN) {
        count[i] = 0; cursor[i] = 0;
        maxkey[i] = 0x007FFFFFu;   // encode(-inf)
        denom[i] = 0.f;
    }
}

// 2. degree histogram
__global__ __launch_bounds__(256) void k_count(const int* __restrict__ dst,
                                               int* __restrict__ count) {
    int e = blockIdx.x * 256 + threadIdx.x;     // NE % 256 == 0
    atomicAdd(&count[dst[e]], 1);
}

// 3. exclusive prefix scan of count -> rowptr
__global__ __launch_bounds__(256) void k_scan(const int* __restrict__ count,
                                              int* __restrict__ rowptr) {
    __shared__ int sdata[256];
    const int tid = threadIdx.x, b = blockIdx.x;
    int pre = 0;
    for (int i = tid; i < b * 256; i += 256) pre += count[i];
    sdata[tid] = pre;
    __syncthreads();
    for (int off = 128; off; off >>= 1) {
        if (tid < off) sdata[tid] += sdata[tid + off];
        __syncthreads();
    }
    const int P = sdata[0];
    __syncthreads();
    const int idx = b * 256 + tid;
    const int c = (idx < NN) ? count[idx] : 0;
    sdata[tid] = c;
    __syncthreads();
    for (int off = 1; off < 256; off <<= 1) {
        int v = (tid >= off) ? sdata[tid - off] : 0;
        __syncthreads();
        sdata[tid] += v;
        __syncthreads();
    }
    if (idx < NN) rowptr[idx] = P + sdata[tid] - c;   // exclusive
}

// 4. fill CSR src lists
__global__ __launch_bounds__(256) void k_fill(const int* __restrict__ src,
                                              const int* __restrict__ dst,
                                              const int* __restrict__ rowptr,
                                              int* __restrict__ cursor,
                                              int* __restrict__ esrc) {
    int e = blockIdx.x * 256 + threadIdx.x;
    int d = dst[e];
    int p = rowptr[d] + atomicAdd(&cursor[d], 1);
    esrc[p] = src[e];
}

// 5. gather-aggregate RAW feat (linearity: segsum(feat@Wt) = segsum(feat)@Wt)
//    one wave per dst, 4-deep pipelined gathers
__global__ __launch_bounds__(256) void k_agg(const float* __restrict__ feat,
                                             const int* __restrict__ rowptr,
                                             const int* __restrict__ count,
                                             const int* __restrict__ esrc,
                                             float* __restrict__ fagg) {
    const int d = blockIdx.x * 4 + threadIdx.y;   // NN % 4 == 0
    const int lane = threadIdx.x;
    const int start = rowptr[d], len = count[d];
    float acc = 0.f;
    for (int base = 0; base < len; base += 64) {
        const int nb = min(64, len - base);
        int sid = (lane < nb) ? esrc[start + base + lane] : 0;
        int j = 0;
        for (; j + 4 <= nb; j += 4) {
            int s0 = __shfl(sid, j, 64);
            int s1 = __shfl(sid, j + 1, 64);
            int s2 = __shfl(sid, j + 2, 64);
            int s3 = __shfl(sid, j + 3, 64);
            float v0 = feat[s0 * 64 + lane];
            float v1 = feat[s1 * 64 + lane];
            float v2 = feat[s2 * 64 + lane];
            float v3 = feat[s3 * 64 + lane];
            acc += v0; acc += v1; acc += v2; acc += v3;
        }
        for (; j < nb; ++j) {
            int s = __shfl(sid, j, 64);
            acc += feat[s * 64 + lane];
        }
    }
    fagg[d * 64 + lane] = acc;
}

// 6. hagg = fagg @ W^T -> d_out, fused t = tanh(hagg)
//    NOTE: t may alias fagg (rows are staged to LDS before the write)
__global__ __launch_bounds__(256) void k_gemm(const float* __restrict__ fagg,
                                              const float* __restrict__ W,
                                              float* __restrict__ hagg,
                                              float* __restrict__ t) {
    __shared__ float sWt[64][65];   // sWt[i][o] = W[o][i]
    __shared__ float sF[4][64];
    const int tx = threadIdx.x, ty = threadIdx.y;
    const int tt = ty * 64 + tx;
    for (int k = tt; k < 4096; k += 256) {
        int o = k >> 6, i = k & 63;
        sWt[i][o] = W[k];
    }
    const int n = blockIdx.x * 4 + ty;          // NN % 4 == 0
    sF[ty][tx] = fagg[n * 64 + tx];
    __syncthreads();
    float acc = 0.f;
#pragma unroll
    for (int i = 0; i < 64; ++i) acc = fmaf(sF[ty][i], sWt[i][tx], acc);
    hagg[n * 64 + tx] = acc;
    t[n * 64 + tx] = tanhf(acc);
}

// 7. quad-per-edge dot: e = leakyrelu(<hagg[src], t[dst]>), original edge order
//    4 lanes per edge; each quad step reads exactly one 64B line per row
__global__ __launch_bounds__(256) void k_edge(const float* __restrict__ hagg,
                                              const float* __restrict__ t,
                                              const int* __restrict__ src,
                                              const int* __restrict__ dst,
                                              float* __restrict__ ebuf,
                                              unsigned* __restrict__ maxkey) {
    const int tid = threadIdx.x;
    const int lane = tid & 63;
    const int q = lane & 3;
    const int e = blockIdx.x * 64 + (tid >> 6) * 16 + (lane >> 2);  // NE%64==0
    const int s = src[e], d = dst[e];
    const float4* A = (const float4*)(hagg + (size_t)s * 64);
    const float4* B = (const float4*)(t + (size_t)d * 64);
    float acc = 0.f;
#pragma unroll
    for (int k = 0; k < 4; ++k) {
        float4 a = A[k * 4 + q];
        float4 b = B[k * 4 + q];
        acc = fmaf(a.x, b.x, acc);
        acc = fmaf(a.y, b.y, acc);
        acc = fmaf(a.z, b.z, acc);
        acc = fmaf(a.w, b.w, acc);
    }
    acc += __shfl_xor(acc, 1, 64);
    acc += __shfl_xor(acc, 2, 64);
    if (q == 0) {
        float ev = acc >= 0.f ? acc : NEG * acc;
        ebuf[e] = ev;
        atomicMax(&maxkey[d], fkey(ev));
    }
}

// 8. x = exp(e - max[dst]); denom[dst] += x
__global__ __launch_bounds__(256) void k_exp(const int* __restrict__ dst,
                                             const unsigned* __restrict__ maxkey,
                                             float* __restrict__ ebuf,
                                             float* __restrict__ denom) {
    int e = blockIdx.x * 256 + threadIdx.x;
    int d = dst[e];
    float x = expf(ebuf[e] - fdec(maxkey[d]));
    ebuf[e] = x;
    atomicAdd(&denom[d], x);
}

// 9. e_soft = x / denom[dst]  (original order, coalesced)
__global__ __launch_bounds__(256) void k_div(const int* __restrict__ dst,
                                             const float* __restrict__ ebuf,
                                             const float* __restrict__ denom,
                                             float* __restrict__ out_e) {
    int e = blockIdx.x * 256 + threadIdx.x;
    out_e[e] = ebuf[e] / denom[dst[e]];
}

extern "C" void kernel_launch(void* const* d_in, const int* in_sizes, int n_in,
                              void* d_out, int out_size, void* d_ws, size_t ws_size,
                              hipStream_t stream) {
    const float* feat = (const float*)d_in[0];
    const float* W    = (const float*)d_in[1];
    const int*   src  = (const int*)d_in[2];
    const int*   dst  = (const int*)d_in[3];

    float* out    = (float*)d_out;
    float* hagg   = out;               // NN*DD
    float* e_soft = out + NN * DD;     // NE

    float*    fagg   = (float*)d_ws;              // NN*DD (later aliased as t)
    float*    t      = fagg;                      // alias: gemm reads row->LDS before write
    float*    ebuf   = fagg + NN * DD;            // NE
    int*      count  = (int*)(ebuf + NE);         // NN
    int*      cursor = count + NN;                // NN
    int*      rowptr = cursor + NN;               // NN
    unsigned* maxkey = (unsigned*)(rowptr + NN);  // NN
    float*    denom  = (float*)(maxkey + NN);     // NN
    int*      esrc   = (int*)(denom + NN);        // NE

    dim3 b64x4(64, 4);
    k_init <<<(NN + 255) / 256, 256, 0, stream>>>(count, cursor, maxkey, denom);
    k_count<<<NE / 256, 256, 0, stream>>>(dst, count);
    k_scan <<<(NN + 255) / 256, 256, 0, stream>>>(count, rowptr);
    k_fill <<<NE / 256, 256, 0, stream>>>(src, dst, rowptr, cursor, esrc);
    k_agg  <<<NN / 4, b64x4, 0, stream>>>(feat, rowptr, count, esrc, fagg);
    k_gemm <<<NN / 4, b64x4, 0, stream>>>(fagg, W, hagg, t);
    k_edge <<<NE / 64, 256, 0, stream>>>(hagg, t, src, dst, ebuf, maxkey);
    k_exp  <<<NE / 256, 256, 0, stream>>>(dst, maxkey, ebuf, denom);
    k_div  <<<NE / 256, 256, 0, stream>>>(dst, ebuf, denom, e_soft);
}

// Round 4
// 209.397 us; speedup vs baseline: 1.9438x; 1.3726x over previous
//
#include <hip/hip_runtime.h>

#define NN 50000
#define NE 800000
#define NEG 0.2f

// 1. init per-call scratch state
__global__ __launch_bounds__(256) void k_init(int* count, int* cursor) {
    int i = blockIdx.x * 256 + threadIdx.x;
    if (i < NN) { count[i] = 0; cursor[i] = 0; }
}

// 2. degree histogram
__global__ __launch_bounds__(256) void k_count(const int* __restrict__ dst,
                                               int* __restrict__ count) {
    int e = blockIdx.x * 256 + threadIdx.x;     // NE % 256 == 0
    atomicAdd(&count[dst[e]], 1);
}

// 3. exclusive prefix scan of count -> rowptr
__global__ __launch_bounds__(256) void k_scan(const int* __restrict__ count,
                                              int* __restrict__ rowptr) {
    __shared__ int sdata[256];
    const int tid = threadIdx.x, b = blockIdx.x;
    int pre = 0;
    for (int i = tid; i < b * 256; i += 256) pre += count[i];
    sdata[tid] = pre;
    __syncthreads();
    for (int off = 128; off; off >>= 1) {
        if (tid < off) sdata[tid] += sdata[tid + off];
        __syncthreads();
    }
    const int P = sdata[0];
    __syncthreads();
    const int idx = b * 256 + tid;
    const int c = (idx < NN) ? count[idx] : 0;
    sdata[tid] = c;
    __syncthreads();
    for (int off = 1; off < 256; off <<= 1) {
        int v = (tid >= off) ? sdata[tid - off] : 0;
        __syncthreads();
        sdata[tid] += v;
        __syncthreads();
    }
    if (idx < NN) rowptr[idx] = P + sdata[tid] - c;   // exclusive
}

// 4. fill CSR src list + inverse permutation pos[e] (coalesced write)
__global__ __launch_bounds__(256) void k_fill(const int* __restrict__ src,
                                              const int* __restrict__ dst,
                                              const int* __restrict__ rowptr,
                                              int* __restrict__ cursor,
                                              int* __restrict__ esrc,
                                              int* __restrict__ pos) {
    int e = blockIdx.x * 256 + threadIdx.x;
    int d = dst[e];
    int p = rowptr[d] + atomicAdd(&cursor[d], 1);
    esrc[p] = src[e];
    pos[e] = p;
}

// 5. fused gather-aggregate(feat) + GEMM: hagg[d] = (sum_src feat[src]) @ W^T
//    one wave per dst; row staged through LDS for the in-block transpose GEMM
__global__ __launch_bounds__(256) void k_aggemm(const float* __restrict__ feat,
                                                const float* __restrict__ W,
                                                const int* __restrict__ rowptr,
                                                const int* __restrict__ count,
                                                const int* __restrict__ esrc,
                                                float* __restrict__ hagg) {
    __shared__ float sWt[64][65];   // sWt[i][o] = W[o][i]
    __shared__ float sF[4][64];
    const int lane = threadIdx.x, w = threadIdx.y;
    const int t = w * 64 + lane;
    for (int k = t; k < 4096; k += 256) sWt[k & 63][k >> 6] = W[k];
    const int d = blockIdx.x * 4 + w;           // NN % 4 == 0
    const int start = rowptr[d], len = count[d];
    float acc = 0.f;
    for (int base = 0; base < len; base += 64) {
        const int nb = min(64, len - base);
        int sid = (lane < nb) ? esrc[start + base + lane] : 0;
        int j = 0;
        for (; j + 4 <= nb; j += 4) {
            int s0 = __shfl(sid, j, 64);
            int s1 = __shfl(sid, j + 1, 64);
            int s2 = __shfl(sid, j + 2, 64);
            int s3 = __shfl(sid, j + 3, 64);
            float v0 = feat[(size_t)s0 * 64 + lane];
            float v1 = feat[(size_t)s1 * 64 + lane];
            float v2 = feat[(size_t)s2 * 64 + lane];
            float v3 = feat[(size_t)s3 * 64 + lane];
            acc += v0; acc += v1; acc += v2; acc += v3;
        }
        for (; j < nb; ++j) {
            int s = __shfl(sid, j, 64);
            acc += feat[(size_t)s * 64 + lane];
        }
    }
    sF[w][lane] = acc;
    __syncthreads();
    float o = 0.f;
#pragma unroll
    for (int i = 0; i < 64; ++i) o = fmaf(sF[w][i], sWt[i][lane], o);
    hagg[(size_t)d * 64 + lane] = o;
}

// 6. fused edge-dot + leaky-relu + softmax stats, CSR order.
//    One wave per dst; tanh(hagg[d]) computed ONCE into LDS, picked up as
//    per-lane quad chunks. Quad-per-edge: 16 edges/wave-step, coalesced
//    64B-line reads of hagg[src], quad reduce via 2 shfl_xor. No atomics.
__global__ __launch_bounds__(256) void k_soft(const float* __restrict__ hagg,
                                              const int* __restrict__ rowptr,
                                              const int* __restrict__ count,
                                              const int* __restrict__ esrc,
                                              float* __restrict__ ebuf,
                                              float2* __restrict__ minv) {
    __shared__ float sT[4][64];
    const int lane = threadIdx.x, w = threadIdx.y;
    const int q = lane & 3, slot = lane >> 2;
    const int d = blockIdx.x * 4 + w;           // NN % 4 == 0
    const int start = rowptr[d], len = count[d];
    sT[w][lane] = tanhf(hagg[(size_t)d * 64 + lane]);
    __syncthreads();
    float4 tq[4];
    const float4* sTw = (const float4*)sT[w];
#pragma unroll
    for (int k = 0; k < 4; ++k) tq[k] = sTw[k * 4 + q];   // broadcast reads

    float m = -3.4e38f;
    for (int base = 0; base < len; base += 16) {
        if (base + slot < len) {                 // quad-uniform predicate
            const int p = start + base + slot;
            const int s = esrc[p];
            const float4* A = (const float4*)(hagg + (size_t)s * 64);
            float acc = 0.f;
#pragma unroll
            for (int k = 0; k < 4; ++k) {
                float4 a = A[k * 4 + q];
                acc = fmaf(a.x, tq[k].x, acc);
                acc = fmaf(a.y, tq[k].y, acc);
                acc = fmaf(a.z, tq[k].z, acc);
                acc = fmaf(a.w, tq[k].w, acc);
            }
            acc += __shfl_xor(acc, 1, 64);       // quad-internal, safe
            acc += __shfl_xor(acc, 2, 64);
            float ev = acc >= 0.f ? acc : NEG * acc;
            m = fmaxf(m, ev);
            if (q == 0) ebuf[p] = ev;            // 16 consecutive dwords
        }
    }
#pragma unroll
    for (int off = 4; off < 64; off <<= 1) m = fmaxf(m, __shfl_xor(m, off, 64));

    float ss = 0.f;
    for (int base = 0; base < len; base += 64) { // full-wave coalesced re-read
        int idx = base + lane;
        float x = (idx < len) ? expf(ebuf[start + idx] - m) : 0.f;
#pragma unroll
        for (int off = 1; off < 64; off <<= 1) x += __shfl_xor(x, off, 64);
        ss += x;
    }
    if (lane == 0 && len > 0) minv[d] = make_float2(m, 1.f / ss);
}

// 7. e_soft[e] = exp(ev[pos[e]] - m[dst]) * inv[dst]  — coalesced in/out
__global__ __launch_bounds__(256) void k_remap(const int* __restrict__ dst,
                                               const int* __restrict__ pos,
                                               const float* __restrict__ ebuf,
                                               const float2* __restrict__ minv,
                                               float* __restrict__ out_e) {
    int e = blockIdx.x * 256 + threadIdx.x;
    float2 mi = minv[dst[e]];
    out_e[e] = expf(ebuf[pos[e]] - mi.x) * mi.y;
}

extern "C" void kernel_launch(void* const* d_in, const int* in_sizes, int n_in,
                              void* d_out, int out_size, void* d_ws, size_t ws_size,
                              hipStream_t stream) {
    const float* feat = (const float*)d_in[0];
    const float* W    = (const float*)d_in[1];
    const int*   src  = (const int*)d_in[2];
    const int*   dst  = (const int*)d_in[3];

    float* out    = (float*)d_out;
    float* hagg   = out;               // NN*64
    float* e_soft = out + NN * 64;     // NE

    float*  ebuf   = (float*)d_ws;            // NE
    int*    count  = (int*)(ebuf + NE);       // NN
    int*    cursor = count + NN;              // NN
    int*    rowptr = cursor + NN;             // NN
    int*    esrc   = rowptr + NN;             // NE
    int*    pos    = esrc + NE;               // NE
    float2* minv   = (float2*)(pos + NE);     // NN

    dim3 b64x4(64, 4);
    k_init  <<<(NN + 255) / 256, 256, 0, stream>>>(count, cursor);
    k_count <<<NE / 256, 256, 0, stream>>>(dst, count);
    k_scan  <<<(NN + 255) / 256, 256, 0, stream>>>(count, rowptr);
    k_fill  <<<NE / 256, 256, 0, stream>>>(src, dst, rowptr, cursor, esrc, pos);
    k_aggemm<<<NN / 4, b64x4, 0, stream>>>(feat, W, rowptr, count, esrc, hagg);
    k_soft  <<<NN / 4, b64x4, 0, stream>>>(hagg, rowptr, count, esrc, ebuf, minv);
    k_remap <<<NE / 256, 256, 0, stream>>>(dst, pos, ebuf, minv, e_soft);
}

// Round 6
// 198.868 us; speedup vs baseline: 2.0467x; 1.0529x over previous
//
#include <hip/hip_runtime.h>

#define NN 50000
#define NE 800000
#define NEG 0.2f

typedef unsigned short ushort_t;

// 1. init per-call scratch state
__global__ __launch_bounds__(256) void k_init(int* count, int* cursor) {
    int i = blockIdx.x * 256 + threadIdx.x;
    if (i < NN) { count[i] = 0; cursor[i] = 0; }
}

// 2. degree histogram
__global__ __launch_bounds__(256) void k_count(const int* __restrict__ dst,
                                               int* __restrict__ count) {
    int e = blockIdx.x * 256 + threadIdx.x;     // NE % 256 == 0
    atomicAdd(&count[dst[e]], 1);
}

// 3. exclusive prefix scan of count -> rowptr
__global__ __launch_bounds__(256) void k_scan(const int* __restrict__ count,
                                              int* __restrict__ rowptr) {
    __shared__ int sdata[256];
    const int tid = threadIdx.x, b = blockIdx.x;
    int pre = 0;
    for (int i = tid; i < b * 256; i += 256) pre += count[i];
    sdata[tid] = pre;
    __syncthreads();
    for (int off = 128; off; off >>= 1) {
        if (tid < off) sdata[tid] += sdata[tid + off];
        __syncthreads();
    }
    const int P = sdata[0];
    __syncthreads();
    const int idx = b * 256 + tid;
    const int c = (idx < NN) ? count[idx] : 0;
    sdata[tid] = c;
    __syncthreads();
    for (int off = 1; off < 256; off <<= 1) {
        int v = (tid >= off) ? sdata[tid - off] : 0;
        __syncthreads();
        sdata[tid] += v;
        __syncthreads();
    }
    if (idx < NN) rowptr[idx] = P + sdata[tid] - c;   // exclusive
}

// 4. fill CSR src list (ushort payload: halves the scatter region) + pos[e]
__global__ __launch_bounds__(256) void k_fill(const int* __restrict__ src,
                                              const int* __restrict__ dst,
                                              const int* __restrict__ rowptr,
                                              int* __restrict__ cursor,
                                              ushort_t* __restrict__ esrc,
                                              int* __restrict__ pos) {
    int e = blockIdx.x * 256 + threadIdx.x;
    int d = dst[e];
    int p = rowptr[d] + atomicAdd(&cursor[d], 1);
    esrc[p] = (ushort_t)src[e];
    pos[e] = p;
}

// 5. fused gather-aggregate(feat) + GEMM: hagg[d] = (sum_src feat[src]) @ W^T
//    One wave per dst. 16 lanes per edge, float4 per lane -> each wave-instr
//    fetches 4 edges x 256B = 1KB.
//    NOTE: __shfl must be UNCONDITIONAL — a shuffle under the divergent
//    `slot < nb` guard can read from an exec-masked-off source lane
//    (undefined on CDNA). Only the load/accumulate is predicated.
__global__ __launch_bounds__(256) void k_aggemm(const float* __restrict__ feat,
                                                const float* __restrict__ W,
                                                const int* __restrict__ rowptr,
                                                const int* __restrict__ count,
                                                const ushort_t* __restrict__ esrc,
                                                float* __restrict__ hagg) {
    __shared__ float sWt[64][65];   // sWt[i][o] = W[o][i]
    __shared__ float4 sF4[4][16];
    const int lane = threadIdx.x, w = threadIdx.y;
    const int g = lane >> 4, il = lane & 15;    // subgroup, lane-in-subgroup
    const int t = w * 64 + lane;
    for (int k = t; k < 4096; k += 256) sWt[k & 63][k >> 6] = W[k];

    const int d = blockIdx.x * 4 + w;           // NN % 4 == 0
    const int start = rowptr[d], len = count[d];
    const float4* F4 = (const float4*)feat;
    float4 acc = make_float4(0.f, 0.f, 0.f, 0.f);

    for (int base = 0; base < len; base += 64) {
        const int nb = min(64, len - base);
        int sid = (lane < nb) ? (int)esrc[start + base + lane] : 0;
        for (int sub = 0; sub < nb; sub += 16) {
#pragma unroll
            for (int kk = 0; kk < 4; ++kk) {
                const int slot = sub + 4 * g + kk;   // uniform per subgroup
                int s = __shfl(sid, slot & 63, 64);  // ALL lanes execute
                if (slot < nb) {
                    float4 v = F4[(size_t)s * 16 + il];
                    acc.x += v.x; acc.y += v.y; acc.z += v.z; acc.w += v.w;
                }
            }
        }
    }
    // reduce across the 4 subgroups (lanes il, il+16, il+32, il+48)
#pragma unroll
    for (int off = 16; off < 64; off <<= 1) {
        acc.x += __shfl_xor(acc.x, off, 64);
        acc.y += __shfl_xor(acc.y, off, 64);
        acc.z += __shfl_xor(acc.z, off, 64);
        acc.w += __shfl_xor(acc.w, off, 64);
    }
    if (g == 0) sF4[w][il] = acc;               // dims 4*il .. 4*il+3
    __syncthreads();

    const float* sF = (const float*)sF4[w];
    float o = 0.f;
#pragma unroll
    for (int i = 0; i < 64; ++i) o = fmaf(sF[i], sWt[i][lane], o);
    hagg[(size_t)d * 64 + lane] = o;
}

// 6. fused edge-dot + leaky-relu + softmax stats, CSR order.
//    One wave per dst; tanh(hagg[d]) once into LDS; quad-per-edge coalesced
//    gather of hagg[src]; in-wave max and exp-sum; no atomics.
//    (Quad shuffles are safe: the predicate is quad-uniform, so a quad is
//    entirely active or entirely inactive.)
__global__ __launch_bounds__(256) void k_soft(const float* __restrict__ hagg,
                                              const int* __restrict__ rowptr,
                                              const int* __restrict__ count,
                                              const ushort_t* __restrict__ esrc,
                                              float* __restrict__ ebuf,
                                              float2* __restrict__ minv) {
    __shared__ float sT[4][64];
    const int lane = threadIdx.x, w = threadIdx.y;
    const int q = lane & 3, slot = lane >> 2;
    const int d = blockIdx.x * 4 + w;           // NN % 4 == 0
    const int start = rowptr[d], len = count[d];
    sT[w][lane] = tanhf(hagg[(size_t)d * 64 + lane]);
    __syncthreads();
    float4 tq[4];
    const float4* sTw = (const float4*)sT[w];
#pragma unroll
    for (int k = 0; k < 4; ++k) tq[k] = sTw[k * 4 + q];   // broadcast reads

    const float4* H4 = (const float4*)hagg;
    float m = -3.4e38f;
    for (int base = 0; base < len; base += 16) {
        if (base + slot < len) {                 // quad-uniform predicate
            const int p = start + base + slot;
            const int s = (int)esrc[p];
            const size_t r = (size_t)s * 16;
            float acc = 0.f;
#pragma unroll
            for (int k = 0; k < 4; ++k) {
                float4 a = H4[r + k * 4 + q];
                acc = fmaf(a.x, tq[k].x, acc);
                acc = fmaf(a.y, tq[k].y, acc);
                acc = fmaf(a.z, tq[k].z, acc);
                acc = fmaf(a.w, tq[k].w, acc);
            }
            acc += __shfl_xor(acc, 1, 64);       // quad-internal
            acc += __shfl_xor(acc, 2, 64);
            float ev = acc >= 0.f ? acc : NEG * acc;
            m = fmaxf(m, ev);
            if (q == 0) ebuf[p] = ev;            // 16 consecutive dwords
        }
    }
#pragma unroll
    for (int off = 4; off < 64; off <<= 1) m = fmaxf(m, __shfl_xor(m, off, 64));

    float ss = 0.f;
    for (int base = 0; base < len; base += 64) { // full-wave coalesced re-read
        int idx = base + lane;
        float x = (idx < len) ? expf(ebuf[start + idx] - m) : 0.f;
#pragma unroll
        for (int off = 1; off < 64; off <<= 1) x += __shfl_xor(x, off, 64);
        ss += x;
    }
    if (lane == 0 && len > 0) minv[d] = make_float2(m, 1.f / ss);
}

// 7. e_soft[e] = exp(ev[pos[e]] - m[dst]) * inv[dst]  — coalesced in/out
__global__ __launch_bounds__(256) void k_remap(const int* __restrict__ dst,
                                               const int* __restrict__ pos,
                                               const float* __restrict__ ebuf,
                                               const float2* __restrict__ minv,
                                               float* __restrict__ out_e) {
    int e = blockIdx.x * 256 + threadIdx.x;
    float2 mi = minv[dst[e]];
    out_e[e] = expf(ebuf[pos[e]] - mi.x) * mi.y;
}

extern "C" void kernel_launch(void* const* d_in, const int* in_sizes, int n_in,
                              void* d_out, int out_size, void* d_ws, size_t ws_size,
                              hipStream_t stream) {
    const float* feat = (const float*)d_in[0];
    const float* W    = (const float*)d_in[1];
    const int*   src  = (const int*)d_in[2];
    const int*   dst  = (const int*)d_in[3];

    float* out    = (float*)d_out;
    float* hagg   = out;               // NN*64
    float* e_soft = out + NN * 64;     // NE

    float*    ebuf   = (float*)d_ws;              // NE f32
    int*      pos    = (int*)(ebuf + NE);         // NE
    float2*   minv   = (float2*)(pos + NE);       // NN (8B aligned)
    int*      count  = (int*)(minv + NN);         // NN
    int*      cursor = count + NN;                // NN
    int*      rowptr = cursor + NN;               // NN
    ushort_t* esrc   = (ushort_t*)(rowptr + NN);  // NE ushort

    dim3 b64x4(64, 4);
    k_init  <<<(NN + 255) / 256, 256, 0, stream>>>(count, cursor);
    k_count <<<NE / 256, 256, 0, stream>>>(dst, count);
    k_scan  <<<(NN + 255) / 256, 256, 0, stream>>>(count, rowptr);
    k_fill  <<<NE / 256, 256, 0, stream>>>(src, dst, rowptr, cursor, esrc, pos);
    k_aggemm<<<NN / 4, b64x4, 0, stream>>>(feat, W, rowptr, count, esrc, hagg);
    k_soft  <<<NN / 4, b64x4, 0, stream>>>(hagg, rowptr, count, esrc, ebuf, minv);
    k_remap <<<NE / 256, 256, 0, stream>>>(dst, pos, ebuf, minv, e_soft);
}

// Round 7
// 190.862 us; speedup vs baseline: 2.1326x; 1.0419x over previous
//
#include <hip/hip_runtime.h>

#define NN 50000
#define NE 800000
#define NEG 0.2f
#define DPB 32   // dsts per block in k_aggemm (8 per wave)

typedef unsigned short ushort_t;

// 1. init per-call scratch state
__global__ __launch_bounds__(256) void k_init(int* count, int* cursor) {
    int i = blockIdx.x * 256 + threadIdx.x;
    if (i < NN) { count[i] = 0; cursor[i] = 0; }
}

// 2. degree histogram
__global__ __launch_bounds__(256) void k_count(const int* __restrict__ dst,
                                               int* __restrict__ count) {
    int e = blockIdx.x * 256 + threadIdx.x;     // NE % 256 == 0
    atomicAdd(&count[dst[e]], 1);
}

// 3. exclusive prefix scan of count -> rowptr
__global__ __launch_bounds__(256) void k_scan(const int* __restrict__ count,
                                              int* __restrict__ rowptr) {
    __shared__ int sdata[256];
    const int tid = threadIdx.x, b = blockIdx.x;
    int pre = 0;
    for (int i = tid; i < b * 256; i += 256) pre += count[i];
    sdata[tid] = pre;
    __syncthreads();
    for (int off = 128; off; off >>= 1) {
        if (tid < off) sdata[tid] += sdata[tid + off];
        __syncthreads();
    }
    const int P = sdata[0];
    __syncthreads();
    const int idx = b * 256 + tid;
    const int c = (idx < NN) ? count[idx] : 0;
    sdata[tid] = c;
    __syncthreads();
    for (int off = 1; off < 256; off <<= 1) {
        int v = (tid >= off) ? sdata[tid - off] : 0;
        __syncthreads();
        sdata[tid] += v;
        __syncthreads();
    }
    if (idx < NN) rowptr[idx] = P + sdata[tid] - c;   // exclusive
}

// 4. fill CSR src list (ushort payload) + inverse permutation pos[e]
__global__ __launch_bounds__(256) void k_fill(const int* __restrict__ src,
                                              const int* __restrict__ dst,
                                              const int* __restrict__ rowptr,
                                              int* __restrict__ cursor,
                                              ushort_t* __restrict__ esrc,
                                              int* __restrict__ pos) {
    int e = blockIdx.x * 256 + threadIdx.x;
    int d = dst[e];
    int p = rowptr[d] + atomicAdd(&cursor[d], 1);
    esrc[p] = (ushort_t)src[e];
    pos[e] = p;
}

// 5. fused gather-aggregate(feat) + GEMM, W staged ONCE per 32 dsts.
//    sF4[w] is wave-private: the per-dst accumulate->GEMM chain is
//    wave-internal LDS (no barriers needed; only sWt needs the one barrier).
__global__ __launch_bounds__(256) void k_aggemm(const float* __restrict__ feat,
                                                const float* __restrict__ W,
                                                const int* __restrict__ rowptr,
                                                const int* __restrict__ count,
                                                const ushort_t* __restrict__ esrc,
                                                float* __restrict__ hagg) {
    __shared__ float sWt[64][65];   // sWt[i][o] = W[o][i]
    __shared__ float4 sF4[4][16];   // per-wave slice
    const int lane = threadIdx.x, w = threadIdx.y;
    const int g = lane >> 4, il = lane & 15;    // subgroup, lane-in-subgroup
    const int t = w * 64 + lane;
    for (int k = t; k < 4096; k += 256) sWt[k & 63][k >> 6] = W[k];
    __syncthreads();

    const float4* F4 = (const float4*)feat;
    const int d0 = blockIdx.x * DPB;
    for (int dd = 0; dd < DPB; dd += 4) {
        const int d = d0 + dd + w;              // wave-uniform
        const bool act = (d < NN);
        const int start = act ? rowptr[d] : 0;
        const int len   = act ? count[d] : 0;
        float4 acc = make_float4(0.f, 0.f, 0.f, 0.f);
        for (int base = 0; base < len; base += 64) {
            const int nb = min(64, len - base);
            int sid = (lane < nb) ? (int)esrc[start + base + lane] : 0;
            for (int sub = 0; sub < nb; sub += 16) {
#pragma unroll
                for (int kk = 0; kk < 4; ++kk) {
                    const int slot = sub + 4 * g + kk;
                    int s = __shfl(sid, slot & 63, 64);   // unconditional
                    if (slot < nb) {
                        float4 v = F4[(size_t)s * 16 + il];
                        acc.x += v.x; acc.y += v.y; acc.z += v.z; acc.w += v.w;
                    }
                }
            }
        }
#pragma unroll
        for (int off = 16; off < 64; off <<= 1) {
            acc.x += __shfl_xor(acc.x, off, 64);
            acc.y += __shfl_xor(acc.y, off, 64);
            acc.z += __shfl_xor(acc.z, off, 64);
            acc.w += __shfl_xor(acc.w, off, 64);
        }
        if (act) {
            if (g == 0) sF4[w][il] = acc;       // wave-internal RAW via LDS
            const float* sF = (const float*)sF4[w];
            float o = 0.f;
#pragma unroll
            for (int i = 0; i < 64; ++i) o = fmaf(sF[i], sWt[i][lane], o);
            hagg[(size_t)d * 64 + lane] = o;
        }
    }
}

// 6. fused edge-dot + leaky-relu + softmax, CSR order, one wave per dst.
//    Fast path (len<=128): ev kept in unrolled register array, exp computed
//    once, NORMALIZED values written to ebuf. Slow path: 3 passes via ebuf.
__global__ __launch_bounds__(256) void k_soft(const float* __restrict__ hagg,
                                              const int* __restrict__ rowptr,
                                              const int* __restrict__ count,
                                              const ushort_t* __restrict__ esrc,
                                              float* __restrict__ ebuf) {
    __shared__ float sT[4][64];
    const int lane = threadIdx.x, w = threadIdx.y;
    const int q = lane & 3, slot = lane >> 2;
    const int d = blockIdx.x * 4 + w;           // NN % 4 == 0
    const int start = rowptr[d], len = count[d];
    sT[w][lane] = tanhf(hagg[(size_t)d * 64 + lane]);
    __syncthreads();
    float4 tq[4];
    const float4* sTw = (const float4*)sT[w];
#pragma unroll
    for (int k = 0; k < 4; ++k) tq[k] = sTw[k * 4 + q];   // broadcast reads

    const float4* H4 = (const float4*)hagg;
    if (len == 0) return;

    if (len <= 128) {                            // fast path (~always)
        float rev[8];
        float m = -3.0e38f;
#pragma unroll
        for (int it = 0; it < 8; ++it) {
            rev[it] = -3.0e38f;
            const int base = it * 16;
            if (base + slot < len) {             // quad-uniform predicate
                const int p = start + base + slot;
                const int s = (int)esrc[p];
                const size_t r = (size_t)s * 16;
                float acc = 0.f;
#pragma unroll
                for (int k = 0; k < 4; ++k) {
                    float4 a = H4[r + k * 4 + q];
                    acc = fmaf(a.x, tq[k].x, acc);
                    acc = fmaf(a.y, tq[k].y, acc);
                    acc = fmaf(a.z, tq[k].z, acc);
                    acc = fmaf(a.w, tq[k].w, acc);
                }
                acc += __shfl_xor(acc, 1, 64);   // quad-internal
                acc += __shfl_xor(acc, 2, 64);
                rev[it] = acc >= 0.f ? acc : NEG * acc;
                m = fmaxf(m, rev[it]);
            }
        }
#pragma unroll
        for (int off = 4; off < 64; off <<= 1) m = fmaxf(m, __shfl_xor(m, off, 64));
        float ss = 0.f;
#pragma unroll
        for (int it = 0; it < 8; ++it) {
            float x = expf(rev[it] - m);         // invalid slots underflow to 0
            ss += x;
            rev[it] = x;
        }
#pragma unroll
        for (int off = 1; off < 64; off <<= 1) ss += __shfl_xor(ss, off, 64);
        const float inv = 4.f / ss;              // each edge counted by 4 lanes
#pragma unroll
        for (int it = 0; it < 8; ++it) {
            const int base = it * 16;
            if (base + slot < len && q == 0)
                ebuf[start + base + slot] = rev[it] * inv;
        }
    } else {                                     // slow path (rare long rows)
        float m = -3.0e38f;
        for (int base = 0; base < len; base += 16) {
            if (base + slot < len) {
                const int p = start + base + slot;
                const int s = (int)esrc[p];
                const size_t r = (size_t)s * 16;
                float acc = 0.f;
#pragma unroll
                for (int k = 0; k < 4; ++k) {
                    float4 a = H4[r + k * 4 + q];
                    acc = fmaf(a.x, tq[k].x, acc);
                    acc = fmaf(a.y, tq[k].y, acc);
                    acc = fmaf(a.z, tq[k].z, acc);
                    acc = fmaf(a.w, tq[k].w, acc);
                }
                acc += __shfl_xor(acc, 1, 64);
                acc += __shfl_xor(acc, 2, 64);
                float ev = acc >= 0.f ? acc : NEG * acc;
                m = fmaxf(m, ev);
                if (q == 0) ebuf[p] = ev;
            }
        }
#pragma unroll
        for (int off = 4; off < 64; off <<= 1) m = fmaxf(m, __shfl_xor(m, off, 64));
        float ss = 0.f;
        for (int base = 0; base < len; base += 64) {
            int idx = base + lane;
            float x = (idx < len) ? expf(ebuf[start + idx] - m) : 0.f;
#pragma unroll
            for (int off = 1; off < 64; off <<= 1) x += __shfl_xor(x, off, 64);
            ss += x;
        }
        const float inv = 1.f / ss;
        for (int base = 0; base < len; base += 64) {
            int idx = base + lane;
            if (idx < len)
                ebuf[start + idx] = expf(ebuf[start + idx] - m) * inv;
        }
    }
}

// 7. pure permutation gather: e_soft[e] = ebuf[pos[e]]
__global__ __launch_bounds__(256) void k_remap(const int* __restrict__ pos,
                                               const float* __restrict__ ebuf,
                                               float* __restrict__ out_e) {
    int e = blockIdx.x * 256 + threadIdx.x;
    out_e[e] = ebuf[pos[e]];
}

extern "C" void kernel_launch(void* const* d_in, const int* in_sizes, int n_in,
                              void* d_out, int out_size, void* d_ws, size_t ws_size,
                              hipStream_t stream) {
    const float* feat = (const float*)d_in[0];
    const float* W    = (const float*)d_in[1];
    const int*   src  = (const int*)d_in[2];
    const int*   dst  = (const int*)d_in[3];

    float* out    = (float*)d_out;
    float* hagg   = out;               // NN*64
    float* e_soft = out + NN * 64;     // NE

    float*    ebuf   = (float*)d_ws;              // NE f32
    int*      pos    = (int*)(ebuf + NE);         // NE
    int*      count  = pos + NE;                  // NN
    int*      cursor = count + NN;                // NN
    int*      rowptr = cursor + NN;               // NN
    ushort_t* esrc   = (ushort_t*)(rowptr + NN);  // NE ushort

    dim3 b64x4(64, 4);
    k_init  <<<(NN + 255) / 256, 256, 0, stream>>>(count, cursor);
    k_count <<<NE / 256, 256, 0, stream>>>(dst, count);
    k_scan  <<<(NN + 255) / 256, 256, 0, stream>>>(count, rowptr);
    k_fill  <<<NE / 256, 256, 0, stream>>>(src, dst, rowptr, cursor, esrc, pos);
    k_aggemm<<<(NN + DPB - 1) / DPB, b64x4, 0, stream>>>(feat, W, rowptr, count,
                                                         esrc, hagg);
    k_soft  <<<NN / 4, b64x4, 0, stream>>>(hagg, rowptr, count, esrc, ebuf);
    k_remap <<<NE / 256, 256, 0, stream>>>(pos, ebuf, e_soft);
}

// Round 8
// 167.875 us; speedup vs baseline: 2.4246x; 1.1369x over previous
//
#include <hip/hip_runtime.h>
#include <hip/hip_fp16.h>

#define NN 50000
#define NE 800000
#define NEG 0.2f

typedef unsigned short ushort_t;

// unpack 8 halfs (uint4) and accumulate into va[0..7]
__device__ __forceinline__ void acc8(float* va, uint4 v) {
    const __half2* h = (const __half2*)&v;
#pragma unroll
    for (int j = 0; j < 4; ++j) {
        float2 f = __half22float2(h[j]);
        va[2 * j]     += f.x;
        va[2 * j + 1] += f.y;
    }
}
// dot of 8 halfs (uint4) with t[0..7]
__device__ __forceinline__ float dot8(uint4 v, const float* t, float acc) {
    const __half2* h = (const __half2*)&v;
#pragma unroll
    for (int j = 0; j < 4; ++j) {
        float2 f = __half22float2(h[j]);
        acc = fmaf(f.x, t[2 * j], acc);
        acc = fmaf(f.y, t[2 * j + 1], acc);
    }
    return acc;
}

// 1. feat -> fp16 mirror (gather payload), zero count
__global__ __launch_bounds__(256) void k_prep(const float* __restrict__ feat,
                                              __half* __restrict__ feat16,
                                              int* __restrict__ count) {
    int i = blockIdx.x * 256 + threadIdx.x;     // grid*256 == NE == NN*16
    const float4 v = ((const float4*)feat)[i];  // 4 floats per thread
    __half2 a = __floats2half2_rn(v.x, v.y);
    __half2 b = __floats2half2_rn(v.z, v.w);
    ((uint2*)feat16)[i] = make_uint2(*(unsigned*)&a, *(unsigned*)&b);
    if (i < NN) count[i] = 0;
}

// 2. degree histogram + per-edge rank (old count value)
__global__ __launch_bounds__(256) void k_count(const int* __restrict__ dst,
                                               int* __restrict__ count,
                                               int* __restrict__ rank) {
    int e = blockIdx.x * 256 + threadIdx.x;     // NE % 256 == 0
    rank[e] = atomicAdd(&count[dst[e]], 1);
}

// 3. exclusive prefix scan of count -> rowptr
__global__ __launch_bounds__(256) void k_scan(const int* __restrict__ count,
                                              int* __restrict__ rowptr) {
    __shared__ int sdata[256];
    const int tid = threadIdx.x, b = blockIdx.x;
    int pre = 0;
    for (int i = tid; i < b * 256; i += 256) pre += count[i];
    sdata[tid] = pre;
    __syncthreads();
    for (int off = 128; off; off >>= 1) {
        if (tid < off) sdata[tid] += sdata[tid + off];
        __syncthreads();
    }
    const int P = sdata[0];
    __syncthreads();
    const int idx = b * 256 + tid;
    const int c = (idx < NN) ? count[idx] : 0;
    sdata[tid] = c;
    __syncthreads();
    for (int off = 1; off < 256; off <<= 1) {
        int v = (tid >= off) ? sdata[tid - off] : 0;
        __syncthreads();
        sdata[tid] += v;
        __syncthreads();
    }
    if (idx < NN) rowptr[idx] = P + sdata[tid] - c;   // exclusive
}

// 4. fill CSR src list (no atomics: p = rowptr + rank) + pos[e]
__global__ __launch_bounds__(256) void k_fill(const int* __restrict__ src,
                                              const int* __restrict__ dst,
                                              const int* __restrict__ rowptr,
                                              const int* __restrict__ rank,
                                              ushort_t* __restrict__ esrc,
                                              int* __restrict__ pos) {
    int e = blockIdx.x * 256 + threadIdx.x;
    int p = rowptr[dst[e]] + rank[e];
    esrc[p] = (ushort_t)src[e];
    pos[e] = p;
}

// 5. fused gather-aggregate(feat16) + GEMM. 8 dsts/block (2/wave).
//    Gather: 8 lanes/edge x 16B (8 halfs) -> one wave-instr covers 8 edges.
__global__ __launch_bounds__(256) void k_aggemm(const __half* __restrict__ feat16,
                                                const float* __restrict__ W,
                                                const int* __restrict__ rowptr,
                                                const int* __restrict__ count,
                                                const ushort_t* __restrict__ esrc,
                                                float* __restrict__ hagg,
                                                __half* __restrict__ hagg16) {
    __shared__ float sWt[64][65];   // sWt[i][o] = W[o][i]
    __shared__ float sFw[4][64];    // per-wave slice (no cross-wave barrier)
    const int lane = threadIdx.x, w = threadIdx.y;
    const int g = lane >> 3, il = lane & 7;     // 8 subgroups of 8 lanes
    const int t = w * 64 + lane;
    for (int k = t; k < 4096; k += 256) sWt[k & 63][k >> 6] = W[k];
    __syncthreads();

    const uint4* F16 = (const uint4*)feat16;    // row = 8 uint4
    for (int dd = 0; dd < 8; dd += 4) {
        const int d = blockIdx.x * 8 + dd + w;  // NN % 8 == 0 -> always valid
        const int start = rowptr[d], len = count[d];
        float va[8];
#pragma unroll
        for (int j = 0; j < 8; ++j) va[j] = 0.f;
        for (int base = 0; base < len; base += 64) {
            const int nb = min(64, len - base);
            int sid = (lane < nb) ? (int)esrc[start + base + lane] : 0;
            for (int sub = 0; sub < nb; sub += 16) {
                const int slot0 = sub + g;
                const int slot1 = sub + 8 + g;
                int s0 = __shfl(sid, slot0 & 63, 64);   // unconditional
                int s1 = __shfl(sid, slot1 & 63, 64);
                if (slot0 < nb) acc8(va, F16[(size_t)s0 * 8 + il]);
                if (slot1 < nb) acc8(va, F16[(size_t)s1 * 8 + il]);
            }
        }
#pragma unroll
        for (int off = 8; off < 64; off <<= 1)
#pragma unroll
            for (int j = 0; j < 8; ++j) va[j] += __shfl_xor(va[j], off, 64);
        if (g == 0) {
#pragma unroll
            for (int j = 0; j < 8; ++j) sFw[w][il * 8 + j] = va[j];
        }
        // wave-internal LDS RAW (compiler inserts lgkmcnt); no barrier needed
        float o = 0.f;
#pragma unroll
        for (int i = 0; i < 64; ++i) o = fmaf(sFw[w][i], sWt[i][lane], o);
        hagg[(size_t)d * 64 + lane] = o;
        hagg16[(size_t)d * 64 + lane] = __float2half(o);
    }
}

// 6. fused edge-dot + leaky-relu + softmax, CSR order, one wave per dst.
//    Gather side (hagg16) is fp16; dst side tanh stays f32.
__global__ __launch_bounds__(256) void k_soft(const float* __restrict__ hagg,
                                              const __half* __restrict__ hagg16,
                                              const int* __restrict__ rowptr,
                                              const int* __restrict__ count,
                                              const ushort_t* __restrict__ esrc,
                                              float* __restrict__ ebuf) {
    __shared__ float sT[4][64];
    const int lane = threadIdx.x, w = threadIdx.y;
    const int q = lane & 3, slot = lane >> 2;
    const int d = blockIdx.x * 4 + w;           // NN % 4 == 0
    const int start = rowptr[d], len = count[d];
    sT[w][lane] = tanhf(hagg[(size_t)d * 64 + lane]);
    __syncthreads();
    float tq[16];                               // dims 16q .. 16q+15
#pragma unroll
    for (int j = 0; j < 16; ++j) tq[j] = sT[w][16 * q + j];

    const uint4* H16 = (const uint4*)hagg16;    // row = 8 uint4
    if (len == 0) return;

    if (len <= 128) {                            // fast path (~always)
        float rev[8];
        float m = -3.0e38f;
#pragma unroll
        for (int it = 0; it < 8; ++it) {
            rev[it] = -3.0e38f;
            const int base = it * 16;
            if (base + slot < len) {             // quad-uniform predicate
                const int p = start + base + slot;
                const int s = (int)esrc[p];
                uint4 v0 = H16[(size_t)s * 8 + 2 * q];
                uint4 v1 = H16[(size_t)s * 8 + 2 * q + 1];
                float acc = dot8(v0, tq, 0.f);
                acc = dot8(v1, tq + 8, acc);
                acc += __shfl_xor(acc, 1, 64);   // quad-internal
                acc += __shfl_xor(acc, 2, 64);
                rev[it] = acc >= 0.f ? acc : NEG * acc;
                m = fmaxf(m, rev[it]);
            }
        }
#pragma unroll
        for (int off = 4; off < 64; off <<= 1) m = fmaxf(m, __shfl_xor(m, off, 64));
        float ss = 0.f;
#pragma unroll
        for (int it = 0; it < 8; ++it) {
            float x = expf(rev[it] - m);         // invalid slots underflow to 0
            ss += x;
            rev[it] = x;
        }
#pragma unroll
        for (int off = 1; off < 64; off <<= 1) ss += __shfl_xor(ss, off, 64);
        const float inv = 4.f / ss;              // each edge counted by 4 lanes
#pragma unroll
        for (int it = 0; it < 8; ++it) {
            const int base = it * 16;
            if (base + slot < len && q == 0)
                ebuf[start + base + slot] = rev[it] * inv;
        }
    } else {                                     // slow path (rare long rows)
        float m = -3.0e38f;
        for (int base = 0; base < len; base += 16) {
            if (base + slot < len) {
                const int p = start + base + slot;
                const int s = (int)esrc[p];
                uint4 v0 = H16[(size_t)s * 8 + 2 * q];
                uint4 v1 = H16[(size_t)s * 8 + 2 * q + 1];
                float acc = dot8(v0, tq, 0.f);
                acc = dot8(v1, tq + 8, acc);
                acc += __shfl_xor(acc, 1, 64);
                acc += __shfl_xor(acc, 2, 64);
                float ev = acc >= 0.f ? acc : NEG * acc;
                m = fmaxf(m, ev);
                if (q == 0) ebuf[p] = ev;
            }
        }
#pragma unroll
        for (int off = 4; off < 64; off <<= 1) m = fmaxf(m, __shfl_xor(m, off, 64));
        float ss = 0.f;
        for (int base = 0; base < len; base += 64) {
            int idx = base + lane;
            float x = (idx < len) ? expf(ebuf[start + idx] - m) : 0.f;
#pragma unroll
            for (int off = 1; off < 64; off <<= 1) x += __shfl_xor(x, off, 64);
            ss += x;
        }
        const float inv = 1.f / ss;
        for (int base = 0; base < len; base += 64) {
            int idx = base + lane;
            if (idx < len)
                ebuf[start + idx] = expf(ebuf[start + idx] - m) * inv;
        }
    }
}

// 7. pure permutation gather: e_soft[e] = ebuf[pos[e]]
__global__ __launch_bounds__(256) void k_remap(const int* __restrict__ pos,
                                               const float* __restrict__ ebuf,
                                               float* __restrict__ out_e) {
    int e = blockIdx.x * 256 + threadIdx.x;
    out_e[e] = ebuf[pos[e]];
}

extern "C" void kernel_launch(void* const* d_in, const int* in_sizes, int n_in,
                              void* d_out, int out_size, void* d_ws, size_t ws_size,
                              hipStream_t stream) {
    const float* feat = (const float*)d_in[0];
    const float* W    = (const float*)d_in[1];
    const int*   src  = (const int*)d_in[2];
    const int*   dst  = (const int*)d_in[3];

    float* out    = (float*)d_out;
    float* hagg   = out;               // NN*64
    float* e_soft = out + NN * 64;     // NE

    float*    ebuf   = (float*)d_ws;              // NE f32      (3.2 MB)
    int*      pos    = (int*)(ebuf + NE);         // NE
    int*      rank   = pos + NE;                  // NE
    int*      count  = rank + NE;                 // NN
    int*      rowptr = count + NN;                // NN
    ushort_t* esrc   = (ushort_t*)(rowptr + NN);  // NE ushort   (1.6 MB)
    __half*   feat16 = (__half*)(esrc + NE);      // NN*64       (6.4 MB)
    __half*   hagg16 = feat16 + NN * 64;          // NN*64       (6.4 MB)

    dim3 b64x4(64, 4);
    k_prep  <<<NN * 64 / 1024, 256, 0, stream>>>(feat, feat16, count);
    k_count <<<NE / 256, 256, 0, stream>>>(dst, count, rank);
    k_scan  <<<(NN + 255) / 256, 256, 0, stream>>>(count, rowptr);
    k_fill  <<<NE / 256, 256, 0, stream>>>(src, dst, rowptr, rank, esrc, pos);
    k_aggemm<<<NN / 8, b64x4, 0, stream>>>(feat16, W, rowptr, count, esrc,
                                           hagg, hagg16);
    k_soft  <<<NN / 4, b64x4, 0, stream>>>(hagg, hagg16, rowptr, count, esrc, ebuf);
    k_remap <<<NE / 256, 256, 0, stream>>>(pos, ebuf, e_soft);
}

// Round 12
// 167.869 us; speedup vs baseline: 2.4247x; 1.0000x over previous
//
#include <hip/hip_runtime.h>
#include <hip/hip_fp16.h>

#define NN 50000
#define NE 800000
#define NEG 0.2f

typedef unsigned short ushort_t;

// unpack 8 halfs (uint4) and accumulate into va[0..7]
__device__ __forceinline__ void acc8(float* va, uint4 v) {
    const __half2* h = (const __half2*)&v;
#pragma unroll
    for (int j = 0; j < 4; ++j) {
        float2 f = __half22float2(h[j]);
        va[2 * j]     += f.x;
        va[2 * j + 1] += f.y;
    }
}
// dot of 8 halfs (uint4) with t[0..7]
__device__ __forceinline__ float dot8(uint4 v, const float* t, float acc) {
    const __half2* h = (const __half2*)&v;
#pragma unroll
    for (int j = 0; j < 4; ++j) {
        float2 f = __half22float2(h[j]);
        acc = fmaf(f.x, t[2 * j], acc);
        acc = fmaf(f.y, t[2 * j + 1], acc);
    }
    return acc;
}

// 1. feat -> fp16 mirror (gather payload), zero count
__global__ __launch_bounds__(256) void k_prep(const float* __restrict__ feat,
                                              __half* __restrict__ feat16,
                                              int* __restrict__ count) {
    int i = blockIdx.x * 256 + threadIdx.x;
    const float4 v = ((const float4*)feat)[i];
    __half2 a = __floats2half2_rn(v.x, v.y);
    __half2 b = __floats2half2_rn(v.z, v.w);
    ((uint2*)feat16)[i] = make_uint2(*(unsigned*)&a, *(unsigned*)&b);
    if (i < NN) count[i] = 0;
}

// 2. degree histogram + per-edge rank
__global__ __launch_bounds__(256) void k_count(const int* __restrict__ dst,
                                               int* __restrict__ count,
                                               int* __restrict__ rank) {
    int e = blockIdx.x * 256 + threadIdx.x;
    rank[e] = atomicAdd(&count[dst[e]], 1);
}

// 3. exclusive prefix scan of count -> rowptr
__global__ __launch_bounds__(256) void k_scan(const int* __restrict__ count,
                                              int* __restrict__ rowptr) {
    __shared__ int sdata[256];
    const int tid = threadIdx.x, b = blockIdx.x;
    int pre = 0;
    for (int i = tid; i < b * 256; i += 256) pre += count[i];
    sdata[tid] = pre;
    __syncthreads();
    for (int off = 128; off; off >>= 1) {
        if (tid < off) sdata[tid] += sdata[tid + off];
        __syncthreads();
    }
    const int P = sdata[0];
    __syncthreads();
    const int idx = b * 256 + tid;
    const int c = (idx < NN) ? count[idx] : 0;
    sdata[tid] = c;
    __syncthreads();
    for (int off = 1; off < 256; off <<= 1) {
        int v = (tid >= off) ? sdata[tid - off] : 0;
        __syncthreads();
        sdata[tid] += v;
        __syncthreads();
    }
    if (idx < NN) rowptr[idx] = P + sdata[tid] - c;   // exclusive
}

// 4. fill CSR src list (no atomics) + pos[e]
__global__ __launch_bounds__(256) void k_fill(const int* __restrict__ src,
                                              const int* __restrict__ dst,
                                              const int* __restrict__ rowptr,
                                              const int* __restrict__ rank,
                                              ushort_t* __restrict__ esrc,
                                              int* __restrict__ pos) {
    int e = blockIdx.x * 256 + threadIdx.x;
    int p = rowptr[dst[e]] + rank[e];
    esrc[p] = (ushort_t)src[e];
    pos[e] = p;
}

// 5. fused gather-aggregate(feat16) + GEMM — BYTE-EXACT r8 version (proven).
//    NOTE (r9-r11 lesson): do NOT restructure the sFw->GEMM path with typed
//    casts (float stores read as float4): TBAA hides the LDS RAW dependency
//    and the compiler reorders reads above the masked writes. Keep both
//    sides plain scalar float.
__global__ __launch_bounds__(256) void k_aggemm(const __half* __restrict__ feat16,
                                                const float* __restrict__ W,
                                                const int* __restrict__ rowptr,
                                                const int* __restrict__ count,
                                                const ushort_t* __restrict__ esrc,
                                                float* __restrict__ hagg,
                                                __half* __restrict__ hagg16) {
    __shared__ float sWt[64][65];   // sWt[i][o] = W[o][i]
    __shared__ float sFw[4][64];    // per-wave slice (no cross-wave barrier)
    const int lane = threadIdx.x, w = threadIdx.y;
    const int g = lane >> 3, il = lane & 7;     // 8 subgroups of 8 lanes
    const int t = w * 64 + lane;
    for (int k = t; k < 4096; k += 256) sWt[k & 63][k >> 6] = W[k];
    __syncthreads();

    const uint4* F16 = (const uint4*)feat16;    // row = 8 uint4
    for (int dd = 0; dd < 8; dd += 4) {
        const int d = blockIdx.x * 8 + dd + w;  // NN % 8 == 0 -> always valid
        const int start = rowptr[d], len = count[d];
        float va[8];
#pragma unroll
        for (int j = 0; j < 8; ++j) va[j] = 0.f;
        for (int base = 0; base < len; base += 64) {
            const int nb = min(64, len - base);
            int sid = (lane < nb) ? (int)esrc[start + base + lane] : 0;
            for (int sub = 0; sub < nb; sub += 16) {
                const int slot0 = sub + g;
                const int slot1 = sub + 8 + g;
                int s0 = __shfl(sid, slot0 & 63, 64);   // unconditional
                int s1 = __shfl(sid, slot1 & 63, 64);
                if (slot0 < nb) acc8(va, F16[(size_t)s0 * 8 + il]);
                if (slot1 < nb) acc8(va, F16[(size_t)s1 * 8 + il]);
            }
        }
#pragma unroll
        for (int off = 8; off < 64; off <<= 1)
#pragma unroll
            for (int j = 0; j < 8; ++j) va[j] += __shfl_xor(va[j], off, 64);
        if (g == 0) {
#pragma unroll
            for (int j = 0; j < 8; ++j) sFw[w][il * 8 + j] = va[j];
        }
        // wave-internal LDS RAW, same-typed accesses (compiler-visible dep)
        float o = 0.f;
#pragma unroll
        for (int i = 0; i < 64; ++i) o = fmaf(sFw[w][i], sWt[i][lane], o);
        hagg[(size_t)d * 64 + lane] = o;
        hagg16[(size_t)d * 64 + lane] = __float2half(o);
    }
}

// 6. fused edge-dot + leaky-relu + softmax — BYTE-EXACT r8 version (proven).
__global__ __launch_bounds__(256) void k_soft(const float* __restrict__ hagg,
                                              const __half* __restrict__ hagg16,
                                              const int* __restrict__ rowptr,
                                              const int* __restrict__ count,
                                              const ushort_t* __restrict__ esrc,
                                              float* __restrict__ ebuf) {
    __shared__ float sT[4][64];
    const int lane = threadIdx.x, w = threadIdx.y;
    const int q = lane & 3, slot = lane >> 2;
    const int d = blockIdx.x * 4 + w;           // NN % 4 == 0
    const int start = rowptr[d], len = count[d];
    sT[w][lane] = tanhf(hagg[(size_t)d * 64 + lane]);
    __syncthreads();
    float tq[16];                               // dims 16q .. 16q+15
#pragma unroll
    for (int j = 0; j < 16; ++j) tq[j] = sT[w][16 * q + j];

    const uint4* H16 = (const uint4*)hagg16;    // row = 8 uint4
    if (len == 0) return;

    if (len <= 128) {                            // fast path (~always)
        float rev[8];
        float m = -3.0e38f;
#pragma unroll
        for (int it = 0; it < 8; ++it) {
            rev[it] = -3.0e38f;
            const int base = it * 16;
            if (base + slot < len) {             // quad-uniform predicate
                const int p = start + base + slot;
                const int s = (int)esrc[p];
                uint4 v0 = H16[(size_t)s * 8 + 2 * q];
                uint4 v1 = H16[(size_t)s * 8 + 2 * q + 1];
                float acc = dot8(v0, tq, 0.f);
                acc = dot8(v1, tq + 8, acc);
                acc += __shfl_xor(acc, 1, 64);   // quad-internal
                acc += __shfl_xor(acc, 2, 64);
                rev[it] = acc >= 0.f ? acc : NEG * acc;
                m = fmaxf(m, rev[it]);
            }
        }
#pragma unroll
        for (int off = 4; off < 64; off <<= 1) m = fmaxf(m, __shfl_xor(m, off, 64));
        float ss = 0.f;
#pragma unroll
        for (int it = 0; it < 8; ++it) {
            float x = expf(rev[it] - m);         // invalid slots underflow to 0
            ss += x;
            rev[it] = x;
        }
#pragma unroll
        for (int off = 1; off < 64; off <<= 1) ss += __shfl_xor(ss, off, 64);
        const float inv = 4.f / ss;              // each edge counted by 4 lanes
#pragma unroll
        for (int it = 0; it < 8; ++it) {
            const int base = it * 16;
            if (base + slot < len && q == 0)
                ebuf[start + base + slot] = rev[it] * inv;
        }
    } else {                                     // slow path (rare long rows)
        float m = -3.0e38f;
        for (int base = 0; base < len; base += 16) {
            if (base + slot < len) {
                const int p = start + base + slot;
                const int s = (int)esrc[p];
                uint4 v0 = H16[(size_t)s * 8 + 2 * q];
                uint4 v1 = H16[(size_t)s * 8 + 2 * q + 1];
                float acc = dot8(v0, tq, 0.f);
                acc = dot8(v1, tq + 8, acc);
                acc += __shfl_xor(acc, 1, 64);
                acc += __shfl_xor(acc, 2, 64);
                float ev = acc >= 0.f ? acc : NEG * acc;
                m = fmaxf(m, ev);
                if (q == 0) ebuf[p] = ev;
            }
        }
#pragma unroll
        for (int off = 4; off < 64; off <<= 1) m = fmaxf(m, __shfl_xor(m, off, 64));
        float ss = 0.f;
        for (int base = 0; base < len; base += 64) {
            int idx = base + lane;
            float x = (idx < len) ? expf(ebuf[start + idx] - m) : 0.f;
#pragma unroll
            for (int off = 1; off < 64; off <<= 1) x += __shfl_xor(x, off, 64);
            ss += x;
        }
        const float inv = 1.f / ss;
        for (int base = 0; base < len; base += 64) {
            int idx = base + lane;
            if (idx < len)
                ebuf[start + idx] = expf(ebuf[start + idx] - m) * inv;
        }
    }
}

// 7. permutation gather, 4 edges/thread: e_soft[e] = ebuf[pos[e]]
//    (vectorized int4/float4 on the coalesced sides; gathers unchanged)
__global__ __launch_bounds__(256) void k_remap(const int* __restrict__ pos,
                                               const float* __restrict__ ebuf,
                                               float* __restrict__ out_e) {
    int i = blockIdx.x * 256 + threadIdx.x;     // i indexes groups of 4
    if (i >= NE / 4) return;
    int4 p4 = ((const int4*)pos)[i];
    float4 r;
    r.x = ebuf[p4.x];
    r.y = ebuf[p4.y];
    r.z = ebuf[p4.z];
    r.w = ebuf[p4.w];
    ((float4*)out_e)[i] = r;
}

extern "C" void kernel_launch(void* const* d_in, const int* in_sizes, int n_in,
                              void* d_out, int out_size, void* d_ws, size_t ws_size,
                              hipStream_t stream) {
    const float* feat = (const float*)d_in[0];
    const float* W    = (const float*)d_in[1];
    const int*   src  = (const int*)d_in[2];
    const int*   dst  = (const int*)d_in[3];

    float* out    = (float*)d_out;
    float* hagg   = out;               // NN*64
    float* e_soft = out + NN * 64;     // NE

    // ws footprint: 24.4 MB — identical to the r8 layout that passed.
    float*    ebuf   = (float*)d_ws;              // NE f32
    int*      pos    = (int*)(ebuf + NE);         // NE
    int*      rank   = pos + NE;                  // NE
    int*      count  = rank + NE;                 // NN
    int*      rowptr = count + NN;                // NN
    ushort_t* esrc   = (ushort_t*)(rowptr + NN);  // NE ushort
    __half*   feat16 = (__half*)(esrc + NE);      // NN*64 fp16
    __half*   hagg16 = feat16 + NN * 64;          // NN*64 fp16

    dim3 b64x4(64, 4);
    k_prep  <<<NN * 64 / 1024, 256, 0, stream>>>(feat, feat16, count);
    k_count <<<NE / 256, 256, 0, stream>>>(dst, count, rank);
    k_scan  <<<(NN + 255) / 256, 256, 0, stream>>>(count, rowptr);
    k_fill  <<<NE / 256, 256, 0, stream>>>(src, dst, rowptr, rank, esrc, pos);
    k_aggemm<<<NN / 8, b64x4, 0, stream>>>(feat16, W, rowptr, count, esrc,
                                           hagg, hagg16);
    k_soft  <<<NN / 4, b64x4, 0, stream>>>(hagg, hagg16, rowptr, count, esrc, ebuf);
    k_remap <<<(NE / 4 + 255) / 256, 256, 0, stream>>>(pos, ebuf, e_soft);
}